// Round 6
// baseline (2201.848 us; speedup 1.0000x reference)
//
#include <hip/hip_runtime.h>
#include <cstddef>

#define TT 2048   // time steps
#define BB 256    // batch
#define DD 32     // input dim
#define HH 64     // hidden
#define GG 256    // 4*H
#define RPB 16    // batch rows per recurrence block
#define NBLK (BB / RPB)   // 16 blocks

using bf16x8 = __attribute__((ext_vector_type(8))) short;
using f32x4  = __attribute__((ext_vector_type(4))) float;

__device__ __forceinline__ float sigmf(float v) { return 1.0f / (1.0f + __expf(-v)); }
__device__ __forceinline__ float tanhf_(float v) { return 2.0f / (1.0f + __expf(-2.0f * v)) - 1.0f; }

__device__ __forceinline__ ushort f2bf(float f) {
    unsigned u = __float_as_uint(f);
    u = (u + 0x7FFFu + ((u >> 16) & 1u)) >> 16;   // round-to-nearest-even
    return (ushort)u;
}

// Swizzled LDS index for H buffers stored [row(16)][unit(64)] as ushort.
// XOR of row into unit bits 3..5 breaks the 16-way bank conflict of the
// stride-128B column read (G4); bijective per 8-unit group, preserves the
// 8/16B alignment of our 4-unit writes and 8-unit reads.
__device__ __forceinline__ int sidx(int row, int unit) {
    return row * 64 + (unit ^ ((row & 7) << 3));
}

// ---------------- pre-kernel: zx = x@W1 + b1, written in MFMA-C-fragment layout ----------------
// ws[(((blk)*TT + t)*16 + m)*256 + lane*4 + r] = z[b0+ (lane&15)][t][16m + (lane>>4)*4 + r]
__global__ __launch_bounds__(256)
void zx_pre(const float* __restrict__ x, const float* __restrict__ W1,
            const float* __restrict__ b1, float* __restrict__ zx)
{
    const int tb = blockIdx.x;       // t-tile of 8
    const int bb = blockIdx.y;       // batch row
    const int zr = threadIdx.x;      // z-row (gate-major column of W1), 0..255
    __shared__ float xs[8][DD];

    const float* xb = x + ((size_t)bb * TT + (size_t)tb * 8) * DD;
    xs[zr >> 5][zr & 31] = xb[zr];
    __syncthreads();

    float wcol[DD];
    #pragma unroll
    for (int d = 0; d < DD; ++d) wcol[d] = W1[d * GG + zr];
    const float bias = b1[zr];

    const int m = zr >> 4, lg = (zr >> 2) & 3, rs = zr & 3;
    float* base = zx + ((((size_t)(bb >> 4)) * TT + (size_t)tb * 8) * 16 + m) * 256
                     + (lg * 16 + (bb & 15)) * 4 + rs;
    #pragma unroll
    for (int r8 = 0; r8 < 8; ++r8) {
        float z0 = bias, z1 = 0.f, z2 = 0.f, z3 = 0.f;
        #pragma unroll
        for (int d = 0; d < DD; d += 4) {
            z0 += xs[r8][d+0] * wcol[d+0];
            z1 += xs[r8][d+1] * wcol[d+1];
            z2 += xs[r8][d+2] * wcol[d+2];
            z3 += xs[r8][d+3] * wcol[d+3];
        }
        base[(size_t)r8 * 4096] = (z0 + z1) + (z2 + z3);
    }
}

// ---------------- recurrence: 16 rows/block via MFMA ----------------
// 8 waves. Waves 0-3: layer-1 (one step ahead), wave w owns D-tiles {w,w+4,w+8,w+12}
// = all 4 gates of units [16w,16w+16). Waves 4-7: layer-2 + projection, same tiling.
// Thread (lane l): batch row l&15, units 16w + (l>>4)*4 + r (r=0..3), ALL gates in-thread
// -> cell update has zero shuffles. H exchanged via swizzled LDS bf16; 1 barrier/step.
__global__ __launch_bounds__(512, 2)
void dlstm_rec(const float* __restrict__ zx,
               const float* __restrict__ U1,
               const float* __restrict__ W2, const float* __restrict__ U2,
               const float* __restrict__ b2,
               const float* __restrict__ Wd, const float* __restrict__ bd,
               float* __restrict__ out)
{
    const int tid = threadIdx.x, blk = blockIdx.x;
    const int wid = tid >> 6, l = tid & 63;
    const int lg = l >> 4, lr = l & 15;
    const int w = wid & 3;

    __shared__ ushort Hs1[2][RPB * 64];
    __shared__ ushort Hs2[2][RPB * 64];
    __shared__ float  PP[2][4][16];

    for (int i = tid; i < RPB * 64; i += 512) {
        Hs1[0][i] = 0; Hs1[1][i] = 0; Hs2[0][i] = 0; Hs2[1][i] = 0;
    }
    if (tid < 128) ((float*)PP)[tid] = 0.f;
    __syncthreads();

    if (wid < 4) {
        // ---------------- layer-1 engine: computes h1(n) at iter n ----------------
        bf16x8 a1[4][2];   // A-frags of U1^T: tile m=w+4gp, K-halves
        #pragma unroll
        for (int gp = 0; gp < 4; ++gp) {
            const int col = 16 * (w + 4 * gp) + lr;
            #pragma unroll
            for (int k = 0; k < 2; ++k) {
                const int kr = 32 * k + lg * 8;
                #pragma unroll
                for (int j = 0; j < 8; ++j) a1[gp][k][j] = (short)f2bf(U1[(kr + j) * GG + col]);
            }
        }
        const float bd0 = bd[0];
        const float* zxb = zx + (size_t)blk * TT * 4096 + (size_t)l * 4;
        f32x4 zc[4], zn[4];
        #pragma unroll
        for (int gp = 0; gp < 4; ++gp) zc[gp] = *(const f32x4*)(zxb + (w + 4 * gp) * 256);
        float c1[4] = {0.f, 0.f, 0.f, 0.f};

        for (int n = 0; n < TT + 2; ++n) {
            const int p = n & 1;
            if (n < TT) {
                const size_t tn = (n + 1 < TT) ? (size_t)(n + 1) : (size_t)n;
                #pragma unroll
                for (int gp = 0; gp < 4; ++gp)
                    zn[gp] = *(const f32x4*)(zxb + tn * 4096 + (w + 4 * gp) * 256);

                bf16x8 hb[2];
                #pragma unroll
                for (int k = 0; k < 2; ++k)
                    hb[k] = *(const bf16x8*)&Hs1[p][sidx(lr, 32 * k + lg * 8)];

                f32x4 acc[4];
                #pragma unroll
                for (int gp = 0; gp < 4; ++gp) {
                    acc[gp] = __builtin_amdgcn_mfma_f32_16x16x32_bf16(a1[gp][0], hb[0], zc[gp], 0, 0, 0);
                    acc[gp] = __builtin_amdgcn_mfma_f32_16x16x32_bf16(a1[gp][1], hb[1], acc[gp], 0, 0, 0);
                }
                ushort hp[4];
                #pragma unroll
                for (int r = 0; r < 4; ++r) {
                    float gi = sigmf(acc[0][r]);
                    float gf = sigmf(acc[1][r]);
                    float gc = tanhf_(acc[2][r]);
                    float go = sigmf(acc[3][r]);
                    c1[r] = gf * c1[r] + gi * gc;
                    float h = go * tanhf_(c1[r]);
                    hp[r] = f2bf(h);
                }
                uint2 pk;
                pk.x = (uint)hp[0] | ((uint)hp[1] << 16);
                pk.y = (uint)hp[2] | ((uint)hp[3] << 16);
                *(uint2*)&Hs1[p ^ 1][sidx(lr, 16 * w + lg * 4)] = pk;
                #pragma unroll
                for (int gp = 0; gp < 4; ++gp) zc[gp] = zn[gp];
            }
            // out(n-2): partials written by L2 at iter n-1
            if (wid == 0 && l < 16 && n >= 2) {
                float s = PP[p][0][l] + PP[p][1][l] + PP[p][2][l] + PP[p][3][l];
                out[(size_t)(blk * RPB + l) * TT + (n - 2)] = sigmf(s + bd0);
            }
            __syncthreads();
        }
    } else {
        // ---------------- layer-2 engine: computes h2(n-1) at iter n ----------------
        bf16x8 aw[4][2], au[4][2];
        f32x4 ci[4];
        float wd[4];
        #pragma unroll
        for (int gp = 0; gp < 4; ++gp) {
            const int col = 16 * (w + 4 * gp) + lr;
            #pragma unroll
            for (int k = 0; k < 2; ++k) {
                const int kr = 32 * k + lg * 8;
                #pragma unroll
                for (int j = 0; j < 8; ++j) {
                    aw[gp][k][j] = (short)f2bf(W2[(kr + j) * GG + col]);
                    au[gp][k][j] = (short)f2bf(U2[(kr + j) * GG + col]);
                }
            }
            #pragma unroll
            for (int r = 0; r < 4; ++r) ci[gp][r] = b2[64 * gp + 16 * w + lg * 4 + r];
        }
        #pragma unroll
        for (int r = 0; r < 4; ++r) wd[r] = Wd[16 * w + lg * 4 + r];
        float c2[4] = {0.f, 0.f, 0.f, 0.f};

        for (int n = 0; n < TT + 2; ++n) {
            const int p = n & 1;
            if (n >= 1 && n <= TT) {
                bf16x8 hb1[2], hb2[2];
                #pragma unroll
                for (int k = 0; k < 2; ++k) {
                    hb1[k] = *(const bf16x8*)&Hs1[p][sidx(lr, 32 * k + lg * 8)];
                    hb2[k] = *(const bf16x8*)&Hs2[p][sidx(lr, 32 * k + lg * 8)];
                }
                f32x4 acc[4];
                #pragma unroll
                for (int gp = 0; gp < 4; ++gp) {
                    acc[gp] = __builtin_amdgcn_mfma_f32_16x16x32_bf16(aw[gp][0], hb1[0], ci[gp], 0, 0, 0);
                    acc[gp] = __builtin_amdgcn_mfma_f32_16x16x32_bf16(aw[gp][1], hb1[1], acc[gp], 0, 0, 0);
                    acc[gp] = __builtin_amdgcn_mfma_f32_16x16x32_bf16(au[gp][0], hb2[0], acc[gp], 0, 0, 0);
                    acc[gp] = __builtin_amdgcn_mfma_f32_16x16x32_bf16(au[gp][1], hb2[1], acc[gp], 0, 0, 0);
                }
                ushort hp[4];
                float pv = 0.f;
                #pragma unroll
                for (int r = 0; r < 4; ++r) {
                    float gi = sigmf(acc[0][r]);
                    float gf = sigmf(acc[1][r]);
                    float gc = tanhf_(acc[2][r]);
                    float go = sigmf(acc[3][r]);
                    c2[r] = gf * c2[r] + gi * gc;
                    float h = go * tanhf_(c2[r]);
                    hp[r] = f2bf(h);
                    pv += h * wd[r];
                }
                uint2 pk;
                pk.x = (uint)hp[0] | ((uint)hp[1] << 16);
                pk.y = (uint)hp[2] | ((uint)hp[3] << 16);
                *(uint2*)&Hs2[p ^ 1][sidx(lr, 16 * w + lg * 4)] = pk;
                // projection partial for rows: sum this wave's 16 units
                pv += __shfl_xor(pv, 16, 64);
                pv += __shfl_xor(pv, 32, 64);
                if (l < 16) PP[p ^ 1][w][l] = pv;
            }
            __syncthreads();
        }
    }
}

// ---------------- fallback (R2 structure, fp32-exact) if ws too small ----------------
__global__ __launch_bounds__(512, 2)
void dlstm_fallback(const float* __restrict__ x,
                    const float* __restrict__ W1, const float* __restrict__ U1,
                    const float* __restrict__ b1,
                    const float* __restrict__ W2, const float* __restrict__ U2,
                    const float* __restrict__ b2,
                    const float* __restrict__ Wd, const float* __restrict__ bd,
                    float* __restrict__ out)
{
    const int tid = threadIdx.x;
    const int b   = blockIdx.x;
    const int wid = tid >> 6;
    const int l   = tid & 63;
    const int g   = l >> 4;
    const int uo  = l & 15;

    __shared__ __align__(16) float h1b[2][HH];
    __shared__ __align__(16) float h2b[2][HH];
    __shared__ float pbuf[2][4];

    if (tid < HH) { h1b[0][tid] = 0.f; h1b[1][tid] = 0.f; h2b[0][tid] = 0.f; h2b[1][tid] = 0.f; }
    if (tid < 8) pbuf[tid >> 2][tid & 3] = 0.f;
    __syncthreads();

    if (wid < 4) {
        const int u   = (wid << 4) + uo;
        const int col = (g << 6) + u;
        float w1c[DD], u1c[HH];
        #pragma unroll
        for (int d = 0; d < DD; ++d) w1c[d] = W1[d * GG + col];
        #pragma unroll
        for (int j = 0; j < HH; ++j) u1c[j] = U1[j * GG + col];
        const float b1k = b1[col], bd0 = bd[0];
        float c1 = 0.f;
        const float* xrow = x + (size_t)b * (TT * DD);
        float4 xv[8];
        #pragma unroll
        for (int q = 0; q < 8; ++q) xv[q] = ((const float4*)xrow)[q];

        for (int n = 0; n < TT + 2; ++n) {
            const int p = n & 1;
            if (n < TT) {
                const float4* xnp = (const float4*)(xrow + (size_t)((n + 1 < TT) ? n + 1 : n) * DD);
                float4 xn[8];
                #pragma unroll
                for (int q = 0; q < 8; ++q) xn[q] = xnp[q];
                float a0 = b1k, a1 = 0.f, a2 = 0.f, a3 = 0.f;
                #pragma unroll
                for (int q = 0; q < 8; ++q) {
                    a0 += xv[q].x * w1c[4*q+0]; a1 += xv[q].y * w1c[4*q+1];
                    a2 += xv[q].z * w1c[4*q+2]; a3 += xv[q].w * w1c[4*q+3];
                }
                const float4* hp = (const float4*)h1b[p];
                #pragma unroll
                for (int q = 0; q < 16; ++q) {
                    float4 hv = hp[q];
                    a0 += hv.x * u1c[4*q+0]; a1 += hv.y * u1c[4*q+1];
                    a2 += hv.z * u1c[4*q+2]; a3 += hv.w * u1c[4*q+3];
                }
                float z = (a0 + a1) + (a2 + a3);
                float a = (g == 2) ? tanhf_(z) : sigmf(z);
                float p16 = __shfl_xor(a, 16, 64);
                float p32 = __shfl_xor(a, 32, 64);
                float p48 = __shfl_xor(p16, 32, 64);
                float gi = (g==0) ? a   : (g==1) ? p16 : (g==2) ? p32 : p48;
                float gf = (g==0) ? p16 : (g==1) ? a   : (g==2) ? p48 : p32;
                float gc = (g==0) ? p32 : (g==1) ? p48 : (g==2) ? a   : p16;
                float go = (g==0) ? p48 : (g==1) ? p32 : (g==2) ? p16 : a;
                c1 = gf * c1 + gi * gc;
                float h = go * tanhf_(c1);
                if (g == 0) h1b[p ^ 1][u] = h;
                #pragma unroll
                for (int q = 0; q < 8; ++q) xv[q] = xn[q];
            }
            if (tid == 0 && n >= 2) {
                float s = pbuf[p][0] + pbuf[p][1] + pbuf[p][2] + pbuf[p][3];
                out[(size_t)b * TT + (n - 2)] = sigmf(s + bd0);
            }
            __syncthreads();
        }
    } else {
        const int w2i = wid - 4;
        const int u   = (w2i << 4) + uo;
        const int col = (g << 6) + u;
        float w2c[HH], u2c[HH];
        #pragma unroll
        for (int j = 0; j < HH; ++j) w2c[j] = W2[j * GG + col];
        #pragma unroll
        for (int j = 0; j < HH; ++j) u2c[j] = U2[j * GG + col];
        const float b2k = b2[col];
        const float wdk = Wd[u];
        float c2 = 0.f;

        for (int n = 0; n < TT + 2; ++n) {
            const int p = n & 1;
            if (n >= 1 && n <= TT) {
                float d0 = b2k, d1 = 0.f, d2 = 0.f, d3 = 0.f;
                const float4* h1p = (const float4*)h1b[p];
                const float4* h2p = (const float4*)h2b[p];
                #pragma unroll
                for (int q = 0; q < 16; ++q) {
                    float4 hv = h1p[q];
                    d0 += hv.x * w2c[4*q+0]; d1 += hv.y * w2c[4*q+1];
                    d2 += hv.z * w2c[4*q+2]; d3 += hv.w * w2c[4*q+3];
                }
                #pragma unroll
                for (int q = 0; q < 16; ++q) {
                    float4 hv = h2p[q];
                    d0 += hv.x * u2c[4*q+0]; d1 += hv.y * u2c[4*q+1];
                    d2 += hv.z * u2c[4*q+2]; d3 += hv.w * u2c[4*q+3];
                }
                float z = (d0 + d1) + (d2 + d3);
                float a = (g == 2) ? tanhf_(z) : sigmf(z);
                float p16 = __shfl_xor(a, 16, 64);
                float p32 = __shfl_xor(a, 32, 64);
                float p48 = __shfl_xor(p16, 32, 64);
                float gi = (g==0) ? a   : (g==1) ? p16 : (g==2) ? p32 : p48;
                float gf = (g==0) ? p16 : (g==1) ? a   : (g==2) ? p48 : p32;
                float gc = (g==0) ? p32 : (g==1) ? p48 : (g==2) ? a   : p16;
                float go = (g==0) ? p48 : (g==1) ? p32 : (g==2) ? p16 : a;
                c2 = gf * c2 + gi * gc;
                float h = go * tanhf_(c2);
                if (g == 0) h2b[p ^ 1][u] = h;
                float v = (g == 0) ? h * wdk : 0.f;
                v += __shfl_xor(v, 1, 64);
                v += __shfl_xor(v, 2, 64);
                v += __shfl_xor(v, 4, 64);
                v += __shfl_xor(v, 8, 64);
                if (l == 0) pbuf[p ^ 1][w2i] = v;
            }
            __syncthreads();
        }
    }
}

extern "C" void kernel_launch(void* const* d_in, const int* in_sizes, int n_in,
                              void* d_out, int out_size, void* d_ws, size_t ws_size,
                              hipStream_t stream) {
    const float* x  = (const float*)d_in[0];
    const float* W1 = (const float*)d_in[1];
    const float* U1 = (const float*)d_in[2];
    const float* b1 = (const float*)d_in[3];
    const float* W2 = (const float*)d_in[4];
    const float* U2 = (const float*)d_in[5];
    const float* b2 = (const float*)d_in[6];
    const float* Wd = (const float*)d_in[7];
    const float* bd = (const float*)d_in[8];
    float* out = (float*)d_out;

    const size_t need_f32 = (size_t)NBLK * TT * 16 * 256 * sizeof(float);  // 537 MB

    if (ws_size >= need_f32) {
        float* zxw = (float*)d_ws;
        zx_pre<<<dim3(TT / 8, BB), dim3(256), 0, stream>>>(x, W1, b1, zxw);
        dlstm_rec<<<dim3(NBLK), dim3(512), 0, stream>>>(zxw, U1, W2, U2, b2, Wd, bd, out);
    } else {
        dlstm_fallback<<<dim3(BB), dim3(512), 0, stream>>>(x, W1, U1, b1, W2, U2, b2, Wd, bd, out);
    }
}